// Round 12
// baseline (87.922 us; speedup 1.0000x reference)
//
#include <hip/hip_runtime.h>

#define NPTS 4096
#define NBATCH 16
#define THREADS 256
#define QPB 256  // queries per block = 4 waves x 64 (2 A-frags per wave)

typedef __attribute__((ext_vector_type(8))) short short8;
typedef __attribute__((ext_vector_type(16))) float float16v;
typedef unsigned short ushort_t;

static __device__ __forceinline__ unsigned short f2bf(float f) {
  unsigned int u = __builtin_bit_cast(unsigned int, f);
  u = (u + 0x7FFFu + ((u >> 16) & 1u)) >> 16;  // RNE
  return (unsigned short)u;
}
static __device__ __forceinline__ float bf2f(unsigned short h) {
  unsigned int u = ((unsigned int)h) << 16;
  return __builtin_bit_cast(float, u);
}

// Chamfer, fp32, B=16, N=M=4096, d=3, bf16-split 32x32x16 MFMA.
// d2 emitted directly by MFMA (K=13/16 slots; verified absmax 0.0 R9-R11):
//   A (query, u=-2p): [uhx,uhx,ulx, uhy,uhy,uly, uhz,uhz, ulz, 1,1, p2h,p2l, 0*3]
//   B (target):       [thx,tlx,thx, thy,tly,thy, thz,tlz, thz, t2h,t2l, 1,1, 0*3]
// R12 restructure: R8/R10/R11 all plateau at ~36us kernel regardless of
// occupancy/pipelining -> the barrier-locked LDS chunk loop is the limiter
// (vmcnt(0)+lgkmcnt(0) drain every chunk; waves phase-locked). Now:
//  - prep kernel converts points to 32B records in ws once (no conversion
//    VALU in the hot loop),
//  - main kernel loads B-frags per-lane global->register (each dwordx4 is a
//    dense 1KB span; compiler pipelines reg loads with fine vmcnt(N)),
//  - NO LDS, NO __syncthreads in the scan: 64 iters x (2 loads,4 MFMA,32 min3).
// Pipe floors: L2 256MB/34.5TBps = 7.5us, VALU(min3) 3.4us, MFMA 1.7us.

__global__ __launch_bounds__(THREADS) void chamfer_prep(
    const float* __restrict__ shape, const float* __restrict__ tmpl,
    ushort_t* __restrict__ Arec, ushort_t* __restrict__ Brec) {
  const int i = blockIdx.x * THREADS + threadIdx.x;  // point in batch
  const int b = blockIdx.y;
  const int src = blockIdx.z;  // 0=shape, 1=tmpl
  const float* P = (src == 0 ? shape : tmpl) + ((size_t)b * NPTS + i) * 3;
  const float x = P[0], y = P[1], zc = P[2];
  const unsigned short ONE = 0x3F80;

  const size_t idx = ((size_t)(src * NBATCH + b) * NPTS + i) * 16;  // ushorts

  // A-record: u = -2p, plus |p|^2 split (slots exactly as R10 staging).
  {
    const float ux = -2.0f * x, uy = -2.0f * y, uz = -2.0f * zc;
    const float p2 = fmaf(x, x, fmaf(y, y, zc * zc));
    const unsigned short hx = f2bf(ux), hy = f2bf(uy), hz = f2bf(uz);
    const unsigned short lx = f2bf(ux - bf2f(hx)), ly = f2bf(uy - bf2f(hy)),
                         lz = f2bf(uz - bf2f(hz));
    const unsigned short h2 = f2bf(p2), l2 = f2bf(p2 - bf2f(h2));
    short8 v0, v1;
    v0[0] = hx; v0[1] = hx; v0[2] = lx; v0[3] = hy;
    v0[4] = hy; v0[5] = ly; v0[6] = hz; v0[7] = hz;
    v1[0] = lz; v1[1] = ONE; v1[2] = ONE; v1[3] = h2;
    v1[4] = l2; v1[5] = 0;  v1[6] = 0;  v1[7] = 0;
    *(short8*)&Arec[idx] = v0;
    *(short8*)&Arec[idx + 8] = v1;
  }
  // B-record: t split + |t|^2 split (slots exactly as R10 staging).
  {
    const float t2 = fmaf(x, x, fmaf(y, y, zc * zc));
    const unsigned short hx = f2bf(x), hy = f2bf(y), hz = f2bf(zc);
    const unsigned short lx = f2bf(x - bf2f(hx)), ly = f2bf(y - bf2f(hy)),
                         lz = f2bf(zc - bf2f(hz));
    const unsigned short h2 = f2bf(t2), l2 = f2bf(t2 - bf2f(h2));
    short8 v0, v1;
    v0[0] = hx; v0[1] = lx; v0[2] = hx; v0[3] = hy;
    v0[4] = ly; v0[5] = hy; v0[6] = hz; v0[7] = lz;
    v1[0] = hz; v1[1] = h2; v1[2] = l2; v1[3] = ONE;
    v1[4] = ONE; v1[5] = 0; v1[6] = 0; v1[7] = 0;
    *(short8*)&Brec[idx] = v0;
    *(short8*)&Brec[idx + 8] = v1;
  }
}

__global__ __launch_bounds__(THREADS)
__attribute__((amdgpu_waves_per_eu(2, 2)))
void chamfer_main(const ushort_t* __restrict__ Arec,
                  const ushort_t* __restrict__ Brec,
                  float* __restrict__ out) {
  __shared__ float redbuf[4];

  const int qc = blockIdx.x;
  const int b = blockIdx.y;
  const int dir = blockIdx.z;
  // dir 0: queries=shape(src0), targets=tmpl(src1); dir 1 swapped.
  const ushort_t* Ab = Arec + ((size_t)(dir * NBATCH + b) * NPTS) * 16;
  const ushort_t* Bb = Brec + ((size_t)((1 - dir) * NBATCH + b) * NPTS) * 16;

  const int tid = threadIdx.x;
  const int lane = tid & 63;
  const int wave = tid >> 6;
  const int n = lane & 31;   // MFMA row/col
  const int kg = lane >> 5;  // K-group / record half

  // A-frags: wave owns queries qb..qb+63 (two 32-row tiles).
  const int qb = qc * QPB + wave * 64;
  const short8 af0 = *(const short8*)(Ab + (size_t)(qb + n) * 16 + kg * 8);
  const short8 af1 = *(const short8*)(Ab + (size_t)(qb + 32 + n) * 16 + kg * 8);

  const float INF = 3.402823466e38f;
  float acc0[16], acc1[16];
  #pragma unroll
  for (int r = 0; r < 16; ++r) { acc0[r] = INF; acc1[r] = INF; }
  const float16v z = {};

  // Lane-fixed byte offset: lane (n,kg) reads half kg of record n.
  const ushort_t* bp = Bb + n * 16 + kg * 8;

  // Barrier-free scan: 64 iters x (2 dense-1KB loads, 4 MFMA, 32 min3).
  #pragma unroll 4
  for (int tp = 0; tp < NPTS / 64; ++tp) {
    const short8 b0 = *(const short8*)(bp + tp * 1024);        // targets +0..31
    const short8 b1 = *(const short8*)(bp + tp * 1024 + 512);  // targets +32..63
    const float16v d00 = __builtin_amdgcn_mfma_f32_32x32x16_bf16(af0, b0, z, 0, 0, 0);
    const float16v d01 = __builtin_amdgcn_mfma_f32_32x32x16_bf16(af0, b1, z, 0, 0, 0);
    const float16v d10 = __builtin_amdgcn_mfma_f32_32x32x16_bf16(af1, b0, z, 0, 0, 0);
    const float16v d11 = __builtin_amdgcn_mfma_f32_32x32x16_bf16(af1, b1, z, 0, 0, 0);
    #pragma unroll
    for (int r = 0; r < 16; ++r)
      acc0[r] = fminf(fminf(d00[r], d01[r]), acc0[r]);  // v_min3_f32
    #pragma unroll
    for (int r = 0; r < 16; ++r)
      acc1[r] = fminf(fminf(d10[r], d11[r]), acc1[r]);
  }

  // Min across the 32 target-cols within each kg half (verified R8).
  #pragma unroll
  for (int m = 1; m <= 16; m <<= 1) {
    #pragma unroll
    for (int r = 0; r < 16; ++r) {
      acc0[r] = fminf(acc0[r], __shfl_xor(acc0[r], m, 64));
      acc1[r] = fminf(acc1[r], __shfl_xor(acc1[r], m, 64));
    }
  }

  // Epilogue: lanes 0/32 hold disjoint row sets (row=(r&3)+8*(r>>2)+4*kg).
  float s = 0.0f;
  if (n == 0) {
    #pragma unroll
    for (int r = 0; r < 16; ++r) {
      s += sqrtf(fmaxf(acc0[r], 0.0f));
      s += sqrtf(fmaxf(acc1[r], 0.0f));
    }
  }
  s += __shfl_xor(s, 32, 64);  // combine kg=0 / kg=1 partials
  if (lane == 0) redbuf[wave] = s;
  __syncthreads();
  if (tid == 0) {
    // out = 0.01 * mean over 16 batches of per-batch chamfer sums
    atomicAdd(out, (redbuf[0] + redbuf[1] + redbuf[2] + redbuf[3]) * (0.01f / 16.0f));
  }
}

// ---- Fallback (known-correct round-2 kernel) if ws is too small ----
__global__ __launch_bounds__(THREADS) void chamfer_fallback(
    const float* __restrict__ shape, const float* __restrict__ tmpl,
    float* __restrict__ out) {
  __shared__ float4 tile[NPTS];
  const int b = blockIdx.y;
  const int dir = blockIdx.z;
  const float* Pb = (dir == 0 ? shape : tmpl) + (size_t)b * NPTS * 3;
  const float* Tb = (dir == 0 ? tmpl : shape) + (size_t)b * NPTS * 3;
  const float4* T4 = (const float4*)Tb;
  for (int base = threadIdx.x * 4; base < NPTS; base += THREADS * 4) {
    const int k = base >> 2;
    float4 a = T4[3 * k + 0], c = T4[3 * k + 1], d = T4[3 * k + 2];
    tile[base + 0] = make_float4(a.x, a.y, a.z, 0.5f * fmaf(a.x, a.x, fmaf(a.y, a.y, a.z * a.z)));
    tile[base + 1] = make_float4(a.w, c.x, c.y, 0.5f * fmaf(a.w, a.w, fmaf(c.x, c.x, c.y * c.y)));
    tile[base + 2] = make_float4(c.z, c.w, d.x, 0.5f * fmaf(c.z, c.z, fmaf(c.w, c.w, d.x * d.x)));
    tile[base + 3] = make_float4(d.y, d.z, d.w, 0.5f * fmaf(d.y, d.y, fmaf(d.z, d.z, d.w * d.w)));
  }
  __syncthreads();
  const int m0 = blockIdx.x * (THREADS * 2) + threadIdx.x;
  const int m1 = m0 + THREADS;
  const float qx0 = Pb[3 * m0], qy0 = Pb[3 * m0 + 1], qz0 = Pb[3 * m0 + 2];
  const float qx1 = Pb[3 * m1], qy1 = Pb[3 * m1 + 1], qz1 = Pb[3 * m1 + 2];
  const float nx0 = -qx0, ny0 = -qy0, nz0 = -qz0;
  const float nx1 = -qx1, ny1 = -qy1, nz1 = -qz1;
  const float p20 = fmaf(qx0, qx0, fmaf(qy0, qy0, qz0 * qz0));
  const float p21 = fmaf(qx1, qx1, fmaf(qy1, qy1, qz1 * qz1));
  const float INF = 3.402823466e38f;
  float a00 = INF, a01 = INF, a10 = INF, a11 = INF;
  #pragma unroll 2
  for (int n = 0; n < NPTS; n += 2) {
    float4 t0 = tile[n], t1 = tile[n + 1];
    a00 = fminf(a00, fmaf(nx0, t0.x, fmaf(ny0, t0.y, fmaf(nz0, t0.z, t0.w))));
    a10 = fminf(a10, fmaf(nx1, t0.x, fmaf(ny1, t0.y, fmaf(nz1, t0.z, t0.w))));
    a01 = fminf(a01, fmaf(nx0, t1.x, fmaf(ny0, t1.y, fmaf(nz0, t1.z, t1.w))));
    a11 = fminf(a11, fmaf(nx1, t1.x, fmaf(ny1, t1.y, fmaf(nz1, t1.z, t1.w))));
  }
  float s = sqrtf(fmaxf(fmaf(2.0f, fminf(a00, a01), p20), 0.0f)) +
            sqrtf(fmaxf(fmaf(2.0f, fminf(a10, a11), p21), 0.0f));
  #pragma unroll
  for (int off = 32; off > 0; off >>= 1) s += __shfl_down(s, off, 64);
  __syncthreads();
  float* red = (float*)tile;
  if ((threadIdx.x & 63) == 0) red[threadIdx.x >> 6] = s;
  __syncthreads();
  if (threadIdx.x == 0)
    atomicAdd(out, (red[0] + red[1] + red[2] + red[3]) * (0.01f / 16.0f));
}

extern "C" void kernel_launch(void* const* d_in, const int* in_sizes, int n_in,
                              void* d_out, int out_size, void* d_ws, size_t ws_size,
                              hipStream_t stream) {
  const float* shape = (const float*)d_in[0];
  const float* tmpl = (const float*)d_in[1];
  float* out = (float*)d_out;

  // d_out is poisoned to 0xAA before every timed launch; atomics need zeros.
  hipMemsetAsync(out, 0, sizeof(float) * out_size, stream);

  const size_t rec_bytes = (size_t)2 * NBATCH * NPTS * 32;  // 4 MB per table
  if (ws_size >= 2 * rec_bytes) {
    ushort_t* Arec = (ushort_t*)d_ws;
    ushort_t* Brec = (ushort_t*)((char*)d_ws + rec_bytes);
    chamfer_prep<<<dim3(NPTS / THREADS, NBATCH, 2), dim3(THREADS), 0, stream>>>(
        shape, tmpl, Arec, Brec);
    chamfer_main<<<dim3(NPTS / QPB, NBATCH, 2), dim3(THREADS), 0, stream>>>(
        Arec, Brec, out);
  } else {
    dim3 grid(NPTS / (THREADS * 2), NBATCH, 2);
    chamfer_fallback<<<grid, dim3(THREADS), 0, stream>>>(shape, tmpl, out);
  }
}